// Round 5
// baseline (410.407 us; speedup 1.0000x reference)
//
#include <hip/hip_runtime.h>

// ---------- types / helpers ----------
typedef __attribute__((ext_vector_type(8))) short short8;   // 8 bf16 = 4 VGPRs
typedef __attribute__((ext_vector_type(4))) float f32x4;

__device__ __forceinline__ float bf2f(unsigned short u) {
    union { unsigned int i; float f; } x; x.i = ((unsigned int)u) << 16; return x.f;
}
__device__ __forceinline__ unsigned short f2bf(float f) {
    union { float f; unsigned int i; } x; x.f = f;
    unsigned int r = x.i + 0x7fffu + ((x.i >> 16) & 1u);   // RTNE
    return (unsigned short)(r >> 16);
}
__device__ __forceinline__ void async_copy16(const void* g, void* l) {
    __builtin_amdgcn_global_load_lds(
        (const __attribute__((address_space(1))) void*)g,
        (__attribute__((address_space(3))) void*)l,
        16, 0, 0);
}

// ---------- fp32 -> bf16 convert (x) + zero-init of kv/ssq scratch ----------
__global__ __launch_bounds__(256) void conv_f32_bf16(const float* __restrict__ in,
                                                     unsigned short* __restrict__ out,
                                                     float* __restrict__ misc) {
    if (blockIdx.x < 20)            // zero kv[4096] + ssq[16384] (poisoned 0xAA)
        *(float4*)&misc[blockIdx.x * 1024 + threadIdx.x * 4] = make_float4(0.f, 0.f, 0.f, 0.f);
    int i = (blockIdx.x * 256 + threadIdx.x) * 8;
    float4 v0 = *(const float4*)&in[i];
    float4 v1 = *(const float4*)&in[i + 4];
    ushort4 o0, o1;
    o0.x = f2bf(v0.x); o0.y = f2bf(v0.y); o0.z = f2bf(v0.z); o0.w = f2bf(v0.w);
    o1.x = f2bf(v1.x); o1.y = f2bf(v1.y); o1.z = f2bf(v1.z); o1.w = f2bf(v1.w);
    *(ushort4*)&out[i]     = o0;
    *(ushort4*)&out[i + 4] = o1;
}

// ---------- both weight transposes in one launch ----------
__global__ __launch_bounds__(256) void transpose_weights(const float* __restrict__ Wqkv,
                                                         unsigned short* __restrict__ WqkvT,
                                                         const float* __restrict__ Wout,
                                                         unsigned short* __restrict__ WoutT) {
    __shared__ float tile[32][33];
    const int R = 1024;
    const float* in; unsigned short* out; int C, bx;
    if (blockIdx.x < 96) { in = Wqkv; out = WqkvT; C = 3072; bx = blockIdx.x * 32; }
    else                 { in = Wout; out = WoutT; C = 1024; bx = (blockIdx.x - 96) * 32; }
    int by = blockIdx.y * 32;
    int tx = threadIdx.x & 31, ty = threadIdx.x >> 5;
    #pragma unroll
    for (int r = ty; r < 32; r += 8)
        tile[r][tx] = in[(size_t)(by + r) * C + bx + tx];
    __syncthreads();
    #pragma unroll
    for (int r = ty; r < 32; r += 8)
        out[(size_t)(bx + r) * R + by + tx] = f2bf(tile[tx][r]);
}

// ---------- bf16 GEMM: C[M,N] = A[M,K] * Bt[N,K]^T ----------
// BM=BN=128, BK=64, 256 threads (4 waves 2x2), wave = 64x64 via 4x4 MFMA 16x16x32.
// Quad-XOR chunk swizzle (R2-proven conflict-free). LDS = 32768 B exactly -> 5 blocks/CU.
// MODE 0: bf16 out via two-pass 64x136 LDS tile, +bias; q-tiles (y<8) atomicAdd row sumsq.
// MODE 1: fp32 out, acc*rsqrt(ssq[row]) + bias, Bt batched by m-tile (4 x 1M elems).
template<int MODE>
__global__ __launch_bounds__(256) void gemm_bf16(const unsigned short* __restrict__ A, int lda,
                                                 const unsigned short* __restrict__ Bt, int ldb,
                                                 const float* __restrict__ bias,
                                                 float* __restrict__ ssq,
                                                 void* __restrict__ C, int ldc, int K) {
    __shared__ short smem[16384];          // 32768 B: As[128][64] | Bs[128][64]
    short* As = smem;
    short* Bs = smem + 8192;

    const int tid    = threadIdx.x;
    const int lane   = tid & 63;
    const int wid    = tid >> 6;
    const int wave_m = wid >> 1, wave_n = wid & 1;
    const int quad   = lane >> 4;
    const int l16    = lane & 15;
    const int m0     = blockIdx.x * 128;
    const int n0     = blockIdx.y * 128;

    if (MODE == 1) Bt += (size_t)(blockIdx.x >> 5) * 1048576;   // batch = m0/4096

    // hoisted staging offsets (K-loop-invariant)
    size_t aoff[4], boff[4];
    int ldst[4];
    #pragma unroll
    for (int j = 0; j < 4; j++) {
        const int L = j * 256 + tid;
        const int r = L >> 3;
        const int c = ((L & 7) ^ (r & 7)) * 8;     // swizzled source chunk
        aoff[j] = (size_t)(m0 + r) * lda + c;
        boff[j] = (size_t)(n0 + r) * ldb + c;
        ldst[j] = L * 8;
    }
    // hoisted fragment row offsets
    int rA[4], rB[4];
    #pragma unroll
    for (int i = 0; i < 4; i++) { rA[i] = wave_m * 64 + i * 16 + l16;
                                  rB[i] = wave_n * 64 + i * 16 + l16; }

    f32x4 acc[4][4] = {};

    for (int k0 = 0; k0 < K; k0 += 64) {
        __syncthreads();   // previous iter's LDS reads done
        #pragma unroll
        for (int j = 0; j < 4; j++) async_copy16(A  + aoff[j] + k0, &As[ldst[j]]);
        #pragma unroll
        for (int j = 0; j < 4; j++) async_copy16(Bt + boff[j] + k0, &Bs[ldst[j]]);
        __syncthreads();   // drain global_load_lds

        #pragma unroll
        for (int kk = 0; kk < 2; kk++) {
            short8 af[4], bfr[4];
            #pragma unroll
            for (int i = 0; i < 4; i++)
                af[i]  = *(const short8*)&As[rA[i] * 64 + (((quad + kk * 4) ^ (rA[i] & 7)) * 8)];
            #pragma unroll
            for (int j = 0; j < 4; j++)
                bfr[j] = *(const short8*)&Bs[rB[j] * 64 + (((quad + kk * 4) ^ (rB[j] & 7)) * 8)];
            #pragma unroll
            for (int i = 0; i < 4; i++)
                #pragma unroll
                for (int j = 0; j < 4; j++)
                    acc[i][j] = __builtin_amdgcn_mfma_f32_16x16x32_bf16(af[i], bfr[j], acc[i][j], 0, 0, 0);
        }
    }

    // C/D layout: col = lane&15, row = quad*4 + r   [m89/m91]
    if (MODE == 0) {
        // fused q-row sumsq partials (q region = first 8 n-tiles)
        if (blockIdx.y < 8) {
            #pragma unroll
            for (int i = 0; i < 4; i++) {
                float s0 = 0.f, s1 = 0.f, s2 = 0.f, s3 = 0.f;
                #pragma unroll
                for (int j = 0; j < 4; j++) {
                    s0 += acc[i][j][0] * acc[i][j][0];
                    s1 += acc[i][j][1] * acc[i][j][1];
                    s2 += acc[i][j][2] * acc[i][j][2];
                    s3 += acc[i][j][3] * acc[i][j][3];
                }
                #pragma unroll
                for (int m = 1; m < 16; m <<= 1) {   // reduce across the 16 l16 lanes
                    s0 += __shfl_xor(s0, m, 64);
                    s1 += __shfl_xor(s1, m, 64);
                    s2 += __shfl_xor(s2, m, 64);
                    s3 += __shfl_xor(s3, m, 64);
                }
                if (l16 == 0) {
                    const int row = m0 + wave_m * 64 + i * 16 + quad * 4;
                    atomicAdd(&ssq[row + 0], s0);
                    atomicAdd(&ssq[row + 1], s1);
                    atomicAdd(&ssq[row + 2], s2);
                    atomicAdd(&ssq[row + 3], s3);
                }
            }
        }
        // two-pass 64-row epilogue tile (keeps LDS at 32 KB)
        unsigned short* tile = (unsigned short*)smem;   // [64][136] padded = 8704 shorts
        unsigned short* Cp = (unsigned short*)C;
        #pragma unroll
        for (int p = 0; p < 2; p++) {
            __syncthreads();
            if (wave_m == p) {
                #pragma unroll
                for (int j = 0; j < 4; j++) {
                    const int tcol = wave_n * 64 + j * 16 + l16;
                    const float bv = bias[n0 + tcol];
                    #pragma unroll
                    for (int i = 0; i < 4; i++) {
                        const int trow = i * 16 + quad * 4;
                        #pragma unroll
                        for (int r = 0; r < 4; r++)
                            tile[(trow + r) * 136 + tcol] = f2bf(acc[i][j][r] + bv);
                    }
                }
            }
            __syncthreads();
            const int row = tid >> 2;                   // 64 rows, 4 threads/row
            const int col = (tid & 3) * 32;
            short8 v0 = *(const short8*)&tile[row * 136 + col];
            short8 v1 = *(const short8*)&tile[row * 136 + col + 8];
            short8 v2 = *(const short8*)&tile[row * 136 + col + 16];
            short8 v3 = *(const short8*)&tile[row * 136 + col + 24];
            unsigned short* dst = &Cp[(size_t)(m0 + p * 64 + row) * ldc + n0 + col];
            *(short8*)&dst[0]  = v0;
            *(short8*)&dst[8]  = v1;
            *(short8*)&dst[16] = v2;
            *(short8*)&dst[24] = v3;
        }
    } else {
        float* Cp = (float*)C;
        #pragma unroll
        for (int i = 0; i < 4; i++) {
            const int growb = m0 + wave_m * 64 + i * 16 + quad * 4;
            const float4 sq4 = *(const float4*)&ssq[growb];     // 4 contiguous rows
            const float rq0 = rsqrtf(sq4.x), rq1 = rsqrtf(sq4.y);
            const float rq2 = rsqrtf(sq4.z), rq3 = rsqrtf(sq4.w);
            #pragma unroll
            for (int j = 0; j < 4; j++) {
                const int gcol = n0 + wave_n * 64 + j * 16 + l16;
                const float bv = bias[gcol];
                Cp[(size_t)(growb + 0) * ldc + gcol] = acc[i][j][0] * rq0 + bv;
                Cp[(size_t)(growb + 1) * ldc + gcol] = acc[i][j][1] * rq1 + bv;
                Cp[(size_t)(growb + 2) * ldc + gcol] = acc[i][j][2] * rq2 + bv;
                Cp[(size_t)(growb + 3) * ldc + gcol] = acc[i][j][3] * rq3 + bv;
            }
        }
    }
}

// ---------- kv pool: kv[b][d] = sum_t k_hat[t][d] * v[t][d]  (q never touched) ----------
// One wave per 4 rows; wave-shuffle k-norm. grid = 1024 blocks.
__global__ __launch_bounds__(256) void kv_pool(const unsigned short* __restrict__ qkv,
                                               float* __restrict__ kv) {
    __shared__ float kvbuf[1024];
    const int tid = threadIdx.x, lane = tid & 63, wv = tid >> 6;
    *(float4*)&kvbuf[tid * 4] = make_float4(0.f, 0.f, 0.f, 0.f);
    __syncthreads();

    const int row0 = blockIdx.x * 16 + wv * 4;
    float a[4][4] = {};

    for (int rr = 0; rr < 4; rr++) {
        const size_t base = (size_t)(row0 + rr) * 3072;
        float k2 = 0.f;
        float kf[4][4];
        #pragma unroll
        for (int c = 0; c < 4; c++) {
            ushort4 ku = *(const ushort4*)&qkv[base + 1024 + c * 256 + lane * 4];
            kf[c][0] = bf2f(ku.x); kf[c][1] = bf2f(ku.y);
            kf[c][2] = bf2f(ku.z); kf[c][3] = bf2f(ku.w);
            k2 += kf[c][0]*kf[c][0] + kf[c][1]*kf[c][1] + kf[c][2]*kf[c][2] + kf[c][3]*kf[c][3];
        }
        #pragma unroll
        for (int m = 32; m; m >>= 1) k2 += __shfl_xor(k2, m, 64);
        const float rk = rsqrtf(k2);

        #pragma unroll
        for (int c = 0; c < 4; c++) {
            ushort4 vu = *(const ushort4*)&qkv[base + 2048 + c * 256 + lane * 4];
            a[c][0] += kf[c][0] * rk * bf2f(vu.x);
            a[c][1] += kf[c][1] * rk * bf2f(vu.y);
            a[c][2] += kf[c][2] * rk * bf2f(vu.z);
            a[c][3] += kf[c][3] * rk * bf2f(vu.w);
        }
    }
    #pragma unroll
    for (int c = 0; c < 4; c++)
        #pragma unroll
        for (int i = 0; i < 4; i++)
            atomicAdd(&kvbuf[c * 256 + lane * 4 + i], a[c][i]);
    __syncthreads();
    const int b = blockIdx.x >> 8;     // 256 blocks per batch
    #pragma unroll
    for (int i = 0; i < 4; i++)
        atomicAdd(&kv[b * 1024 + tid * 4 + i], kvbuf[tid * 4 + i]);
}

// ---------- W'_b^T[n][k] = WoutT[n][k] * kv[b][k]  (bf16) ----------
__global__ __launch_bounds__(256) void wprep(const unsigned short* __restrict__ WoutT,
                                             const float* __restrict__ kv,
                                             unsigned short* __restrict__ WbT) {
    const int b = blockIdx.x >> 10, n = blockIdx.x & 1023, k = threadIdx.x * 4;
    ushort4 w = *(const ushort4*)&WoutT[n * 1024 + k];
    float4 kvv = *(const float4*)&kv[b * 1024 + k];
    ushort4 o;
    o.x = f2bf(bf2f(w.x) * kvv.x);
    o.y = f2bf(bf2f(w.y) * kvv.y);
    o.z = f2bf(bf2f(w.z) * kvv.z);
    o.w = f2bf(bf2f(w.w) * kvv.w);
    *(ushort4*)&WbT[((size_t)b << 20) + n * 1024 + k] = o;
}

extern "C" void kernel_launch(void* const* d_in, const int* in_sizes, int n_in,
                              void* d_out, int out_size, void* d_ws, size_t ws_size,
                              hipStream_t stream) {
    const float* x    = (const float*)d_in[0];   // (4,4096,1024)
    const float* Wqkv = (const float*)d_in[1];   // (1024,3072)
    const float* bqkv = (const float*)d_in[2];   // (3072)
    const float* Wout = (const float*)d_in[3];   // (1024,1024)
    const float* bout = (const float*)d_in[4];   // (1024)
    float* out = (float*)d_out;                  // (4,4096,1024) fp32

    char* ws = (char*)d_ws;
    unsigned short* x_bf  = (unsigned short*)(ws + 0);           // 32 MB; dead after GEMM1
    unsigned short* WbT   = x_bf;                                // 8 MB, reuses x_bf region
    unsigned short* WqkvT = (unsigned short*)(ws + 33554432);    // 6 MB
    unsigned short* WoutT = (unsigned short*)(ws + 39845888);    // 2 MB
    unsigned short* qkv   = (unsigned short*)(ws + 41943040);    // 96 MB
    float* kv             = (float*)(ws + 142606336);            // 16 KB
    float* ssq            = (float*)(ws + 142622720);            // 64 KB (q row sumsq)

    conv_f32_bf16<<<8192, 256, 0, stream>>>(x, x_bf, kv);        // also zeros kv+ssq
    transpose_weights<<<dim3(128, 32), 256, 0, stream>>>(Wqkv, WqkvT, Wout, WoutT);

    // qkv = x @ Wqkv + bqkv   (M=16384, N=3072, K=1024) -> bf16; fills ssq for q rows
    gemm_bf16<0><<<dim3(128, 24), 256, 0, stream>>>(x_bf, 1024, WqkvT, 1024, bqkv, ssq,
                                                    (void*)qkv, 3072, 1024);

    kv_pool<<<1024, 256, 0, stream>>>(qkv, kv);
    wprep<<<4096, 256, 0, stream>>>(WoutT, kv, WbT);

    // y = rsqrt(ssq) .* (q @ W'_b) + bout   (M=16384, N=1024, K=1024) -> fp32 d_out
    gemm_bf16<1><<<dim3(128, 8), 256, 0, stream>>>(qkv, 3072, WbT, 1024, bout, ssq,
                                                   (void*)out, 1024, 1024);
}

// Round 6
// 406.671 us; speedup vs baseline: 1.0092x; 1.0092x over previous
//
#include <hip/hip_runtime.h>

// ---------- types / helpers ----------
typedef __attribute__((ext_vector_type(8))) short short8;   // 8 bf16 = 4 VGPRs
typedef __attribute__((ext_vector_type(4))) float f32x4;

__device__ __forceinline__ float bf2f(unsigned short u) {
    union { unsigned int i; float f; } x; x.i = ((unsigned int)u) << 16; return x.f;
}
__device__ __forceinline__ unsigned short f2bf(float f) {
    union { float f; unsigned int i; } x; x.f = f;
    unsigned int r = x.i + 0x7fffu + ((x.i >> 16) & 1u);   // RTNE
    return (unsigned short)(r >> 16);
}
__device__ __forceinline__ void async_copy16(const void* g, void* l) {
    __builtin_amdgcn_global_load_lds(
        (const __attribute__((address_space(1))) void*)g,
        (__attribute__((address_space(3))) void*)l,
        16, 0, 0);
}

// ---------- fp32 -> bf16 convert (x) + kv zero-init fold ----------
__global__ __launch_bounds__(256) void conv_f32_bf16(const float* __restrict__ in,
                                                     unsigned short* __restrict__ out,
                                                     float* __restrict__ kv) {
    if (blockIdx.x < 4)             // zero kv[4096] (re-poisoned to 0xAA each call)
        *(float4*)&kv[blockIdx.x * 1024 + threadIdx.x * 4] = make_float4(0.f, 0.f, 0.f, 0.f);
    int i = (blockIdx.x * 256 + threadIdx.x) * 8;
    float4 v0 = *(const float4*)&in[i];
    float4 v1 = *(const float4*)&in[i + 4];
    ushort4 o0, o1;
    o0.x = f2bf(v0.x); o0.y = f2bf(v0.y); o0.z = f2bf(v0.z); o0.w = f2bf(v0.w);
    o1.x = f2bf(v1.x); o1.y = f2bf(v1.y); o1.z = f2bf(v1.z); o1.w = f2bf(v1.w);
    *(ushort4*)&out[i]     = o0;
    *(ushort4*)&out[i + 4] = o1;
}

// ---------- both weight transposes in one launch ----------
__global__ __launch_bounds__(256) void transpose_weights(const float* __restrict__ Wqkv,
                                                         unsigned short* __restrict__ WqkvT,
                                                         const float* __restrict__ Wout,
                                                         unsigned short* __restrict__ WoutT) {
    __shared__ float tile[32][33];
    const int R = 1024;
    const float* in; unsigned short* out; int C, bx;
    if (blockIdx.x < 96) { in = Wqkv; out = WqkvT; C = 3072; bx = blockIdx.x * 32; }
    else                 { in = Wout; out = WoutT; C = 1024; bx = (blockIdx.x - 96) * 32; }
    int by = blockIdx.y * 32;
    int tx = threadIdx.x & 31, ty = threadIdx.x >> 5;
    #pragma unroll
    for (int r = ty; r < 32; r += 8)
        tile[r][tx] = in[(size_t)(by + r) * C + bx + tx];
    __syncthreads();
    #pragma unroll
    for (int r = ty; r < 32; r += 8)
        out[(size_t)(bx + r) * R + by + tx] = f2bf(tile[tx][r]);
}

// ---------- GEMM1 (R4-proven): qkv[M,3072] = x[M,1024] @ WqkvT^T + bqkv, bf16 out ----------
// BM=BN=128, BK=64, 256 threads (4 waves 2x2), wave = 64x64 via 4x4 MFMA 16x16x32.
// Quad-XOR chunk swizzle; one-pass 128x136 LDS epilogue tile (34816 B).
__global__ __launch_bounds__(256) void gemm_qkv(const unsigned short* __restrict__ A, int lda,
                                                const unsigned short* __restrict__ Bt, int ldb,
                                                const float* __restrict__ bias,
                                                unsigned short* __restrict__ C, int ldc, int K) {
    __shared__ short smem[17408];
    short* As = smem;
    short* Bs = smem + 8192;

    const int tid    = threadIdx.x;
    const int lane   = tid & 63;
    const int wid    = tid >> 6;
    const int wave_m = wid >> 1, wave_n = wid & 1;
    const int quad   = lane >> 4;
    const int l16    = lane & 15;
    const int m0     = blockIdx.x * 128;
    const int n0     = blockIdx.y * 128;

    size_t aoff[4], boff[4];
    int ldst[4];
    #pragma unroll
    for (int j = 0; j < 4; j++) {
        const int L = j * 256 + tid;
        const int r = L >> 3;
        const int c = ((L & 7) ^ (r & 7)) * 8;
        aoff[j] = (size_t)(m0 + r) * lda + c;
        boff[j] = (size_t)(n0 + r) * ldb + c;
        ldst[j] = L * 8;
    }
    int rA[4], rB[4];
    #pragma unroll
    for (int i = 0; i < 4; i++) { rA[i] = wave_m * 64 + i * 16 + l16;
                                  rB[i] = wave_n * 64 + i * 16 + l16; }

    f32x4 acc[4][4] = {};

    for (int k0 = 0; k0 < K; k0 += 64) {
        __syncthreads();
        #pragma unroll
        for (int j = 0; j < 4; j++) async_copy16(A  + aoff[j] + k0, &As[ldst[j]]);
        #pragma unroll
        for (int j = 0; j < 4; j++) async_copy16(Bt + boff[j] + k0, &Bs[ldst[j]]);
        __syncthreads();

        #pragma unroll
        for (int kk = 0; kk < 2; kk++) {
            short8 af[4], bfr[4];
            #pragma unroll
            for (int i = 0; i < 4; i++)
                af[i]  = *(const short8*)&As[rA[i] * 64 + (((quad + kk * 4) ^ (rA[i] & 7)) * 8)];
            #pragma unroll
            for (int j = 0; j < 4; j++)
                bfr[j] = *(const short8*)&Bs[rB[j] * 64 + (((quad + kk * 4) ^ (rB[j] & 7)) * 8)];
            #pragma unroll
            for (int i = 0; i < 4; i++)
                #pragma unroll
                for (int j = 0; j < 4; j++)
                    acc[i][j] = __builtin_amdgcn_mfma_f32_16x16x32_bf16(af[i], bfr[j], acc[i][j], 0, 0, 0);
        }
    }

    // C/D layout: col = lane&15, row = quad*4 + r   [m89/m91]
    __syncthreads();
    unsigned short* tile = (unsigned short*)smem;   // [128][136] padded
    #pragma unroll
    for (int j = 0; j < 4; j++) {
        const int tcol = wave_n * 64 + j * 16 + l16;
        const float bv = bias[n0 + tcol];
        #pragma unroll
        for (int i = 0; i < 4; i++) {
            const int trow = wave_m * 64 + i * 16 + quad * 4;
            #pragma unroll
            for (int r = 0; r < 4; r++)
                tile[(trow + r) * 136 + tcol] = f2bf(acc[i][j][r] + bv);
        }
    }
    __syncthreads();
    #pragma unroll
    for (int p = 0; p < 4; p++) {
        const int row = p * 32 + (tid >> 3);
        const int col = (tid & 7) * 16;
        short8 v0 = *(const short8*)&tile[row * 136 + col];
        short8 v1 = *(const short8*)&tile[row * 136 + col + 8];
        *(short8*)&C[(size_t)(m0 + row) * ldc + n0 + col]     = v0;
        *(short8*)&C[(size_t)(m0 + row) * ldc + n0 + col + 8] = v1;
    }
}

// ---------- GEMM2: out[M,1024] = rnq .* (q[M,1024(ld 3072)] @ WbT_b^T) + bout, fp32 ----------
// BM=64, BN=128, BK=64 -> 2048 blocks (vs 1024): doubles per-CU block overlap.
// 24 KB LDS -> 6 blocks/CU; 4 waves 2x2, wave = 32x64 via 2x4 MFMA 16x16x32.
__global__ __launch_bounds__(256) void gemm_out(const unsigned short* __restrict__ A, int lda,
                                                const unsigned short* __restrict__ Bt, int ldb,
                                                const float* __restrict__ bias,
                                                const float* __restrict__ rnq,
                                                float* __restrict__ C, int ldc, int K) {
    __shared__ short smem[12288];          // As[64][64] (8 KB) | Bs[128][64] (16 KB)
    short* As = smem;
    short* Bs = smem + 4096;

    const int tid    = threadIdx.x;
    const int lane   = tid & 63;
    const int wid    = tid >> 6;
    const int wave_m = wid >> 1, wave_n = wid & 1;
    const int quad   = lane >> 4;
    const int l16    = lane & 15;
    const int m0     = blockIdx.x * 64;
    const int n0     = blockIdx.y * 128;

    Bt += (size_t)(blockIdx.x >> 6) * 1048576;   // batch = m0/4096

    size_t aoff[2], boff[4];
    int lasta[2], lastb[4];
    #pragma unroll
    for (int j = 0; j < 2; j++) {
        const int L = j * 256 + tid;           // 512 chunks of A
        const int r = L >> 3;
        const int c = ((L & 7) ^ (r & 7)) * 8;
        aoff[j] = (size_t)(m0 + r) * lda + c;
        lasta[j] = L * 8;
    }
    #pragma unroll
    for (int j = 0; j < 4; j++) {
        const int L = j * 256 + tid;           // 1024 chunks of B
        const int r = L >> 3;
        const int c = ((L & 7) ^ (r & 7)) * 8;
        boff[j] = (size_t)(n0 + r) * ldb + c;
        lastb[j] = L * 8;
    }
    int rA[2], rB[4];
    #pragma unroll
    for (int i = 0; i < 2; i++) rA[i] = wave_m * 32 + i * 16 + l16;
    #pragma unroll
    for (int j = 0; j < 4; j++) rB[j] = wave_n * 64 + j * 16 + l16;

    f32x4 acc[2][4] = {};

    for (int k0 = 0; k0 < K; k0 += 64) {
        __syncthreads();
        #pragma unroll
        for (int j = 0; j < 2; j++) async_copy16(A  + aoff[j] + k0, &As[lasta[j]]);
        #pragma unroll
        for (int j = 0; j < 4; j++) async_copy16(Bt + boff[j] + k0, &Bs[lastb[j]]);
        __syncthreads();

        #pragma unroll
        for (int kk = 0; kk < 2; kk++) {
            short8 af[2], bfr[4];
            #pragma unroll
            for (int i = 0; i < 2; i++)
                af[i]  = *(const short8*)&As[rA[i] * 64 + (((quad + kk * 4) ^ (rA[i] & 7)) * 8)];
            #pragma unroll
            for (int j = 0; j < 4; j++)
                bfr[j] = *(const short8*)&Bs[rB[j] * 64 + (((quad + kk * 4) ^ (rB[j] & 7)) * 8)];
            #pragma unroll
            for (int i = 0; i < 2; i++)
                #pragma unroll
                for (int j = 0; j < 4; j++)
                    acc[i][j] = __builtin_amdgcn_mfma_f32_16x16x32_bf16(af[i], bfr[j], acc[i][j], 0, 0, 0);
        }
    }

    // epilogue: acc * rsnq[row] + bias, scattered fp32 (proven pattern)
    #pragma unroll
    for (int i = 0; i < 2; i++) {
        const int growb = m0 + wave_m * 32 + i * 16 + quad * 4;
        const float4 rq4 = *(const float4*)&rnq[growb];
        #pragma unroll
        for (int j = 0; j < 4; j++) {
            const int gcol = n0 + wave_n * 64 + j * 16 + l16;
            const float bv = bias[gcol];
            C[(size_t)(growb + 0) * ldc + gcol] = acc[i][j][0] * rq4.x + bv;
            C[(size_t)(growb + 1) * ldc + gcol] = acc[i][j][1] * rq4.y + bv;
            C[(size_t)(growb + 2) * ldc + gcol] = acc[i][j][2] * rq4.z + bv;
            C[(size_t)(growb + 3) * ldc + gcol] = acc[i][j][3] * rq4.w + bv;
        }
    }
}

// ---------- per-row q-norm + k-norm + kv pool (R4-proven) ----------
__global__ __launch_bounds__(256) void norm_kv(const unsigned short* __restrict__ qkv,
                                               float* __restrict__ rnq,
                                               float* __restrict__ kv) {
    __shared__ float kvbuf[1024];
    const int tid = threadIdx.x, lane = tid & 63, wv = tid >> 6;
    *(float4*)&kvbuf[tid * 4] = make_float4(0.f, 0.f, 0.f, 0.f);
    __syncthreads();

    const int row0 = blockIdx.x * 16 + wv * 4;
    float a[4][4] = {};

    for (int rr = 0; rr < 4; rr++) {
        const size_t base = (size_t)(row0 + rr) * 3072;
        float q2 = 0.f;
        #pragma unroll
        for (int c = 0; c < 4; c++) {
            ushort4 qu = *(const ushort4*)&qkv[base + c * 256 + lane * 4];
            float x0 = bf2f(qu.x), x1 = bf2f(qu.y), x2 = bf2f(qu.z), x3 = bf2f(qu.w);
            q2 += x0 * x0 + x1 * x1 + x2 * x2 + x3 * x3;
        }
        #pragma unroll
        for (int m = 32; m; m >>= 1) q2 += __shfl_xor(q2, m, 64);
        if (lane == 0) rnq[row0 + rr] = rsqrtf(q2);

        float k2 = 0.f;
        float kf[4][4];
        #pragma unroll
        for (int c = 0; c < 4; c++) {
            ushort4 ku = *(const ushort4*)&qkv[base + 1024 + c * 256 + lane * 4];
            kf[c][0] = bf2f(ku.x); kf[c][1] = bf2f(ku.y);
            kf[c][2] = bf2f(ku.z); kf[c][3] = bf2f(ku.w);
            k2 += kf[c][0]*kf[c][0] + kf[c][1]*kf[c][1] + kf[c][2]*kf[c][2] + kf[c][3]*kf[c][3];
        }
        #pragma unroll
        for (int m = 32; m; m >>= 1) k2 += __shfl_xor(k2, m, 64);
        const float rk = rsqrtf(k2);

        #pragma unroll
        for (int c = 0; c < 4; c++) {
            ushort4 vu = *(const ushort4*)&qkv[base + 2048 + c * 256 + lane * 4];
            a[c][0] += kf[c][0] * rk * bf2f(vu.x);
            a[c][1] += kf[c][1] * rk * bf2f(vu.y);
            a[c][2] += kf[c][2] * rk * bf2f(vu.z);
            a[c][3] += kf[c][3] * rk * bf2f(vu.w);
        }
    }
    #pragma unroll
    for (int c = 0; c < 4; c++)
        #pragma unroll
        for (int i = 0; i < 4; i++)
            atomicAdd(&kvbuf[c * 256 + lane * 4 + i], a[c][i]);
    __syncthreads();
    const int b = blockIdx.x >> 8;
    #pragma unroll
    for (int i = 0; i < 4; i++)
        atomicAdd(&kv[b * 1024 + tid * 4 + i], kvbuf[tid * 4 + i]);
}

// ---------- W'_b^T[n][k] = WoutT[n][k] * kv[b][k]  (bf16) ----------
__global__ __launch_bounds__(256) void wprep(const unsigned short* __restrict__ WoutT,
                                             const float* __restrict__ kv,
                                             unsigned short* __restrict__ WbT) {
    const int b = blockIdx.x >> 10, n = blockIdx.x & 1023, k = threadIdx.x * 4;
    ushort4 w = *(const ushort4*)&WoutT[n * 1024 + k];
    float4 kvv = *(const float4*)&kv[b * 1024 + k];
    ushort4 o;
    o.x = f2bf(bf2f(w.x) * kvv.x);
    o.y = f2bf(bf2f(w.y) * kvv.y);
    o.z = f2bf(bf2f(w.z) * kvv.z);
    o.w = f2bf(bf2f(w.w) * kvv.w);
    *(ushort4*)&WbT[((size_t)b << 20) + n * 1024 + k] = o;
}

extern "C" void kernel_launch(void* const* d_in, const int* in_sizes, int n_in,
                              void* d_out, int out_size, void* d_ws, size_t ws_size,
                              hipStream_t stream) {
    const float* x    = (const float*)d_in[0];   // (4,4096,1024)
    const float* Wqkv = (const float*)d_in[1];   // (1024,3072)
    const float* bqkv = (const float*)d_in[2];   // (3072)
    const float* Wout = (const float*)d_in[3];   // (1024,1024)
    const float* bout = (const float*)d_in[4];   // (1024)
    float* out = (float*)d_out;                  // (4,4096,1024) fp32

    char* ws = (char*)d_ws;
    unsigned short* x_bf  = (unsigned short*)(ws + 0);           // 32 MB; dead after GEMM1
    unsigned short* WbT   = x_bf;                                // 8 MB, reuses x_bf region
    unsigned short* WqkvT = (unsigned short*)(ws + 33554432);    // 6 MB
    unsigned short* WoutT = (unsigned short*)(ws + 39845888);    // 2 MB
    unsigned short* qkv   = (unsigned short*)(ws + 41943040);    // 96 MB
    float* kv             = (float*)(ws + 142606336);            // 16 KB
    float* rnq            = (float*)(ws + 142622720);            // 64 KB

    conv_f32_bf16<<<8192, 256, 0, stream>>>(x, x_bf, kv);        // also zeros kv
    transpose_weights<<<dim3(128, 32), 256, 0, stream>>>(Wqkv, WqkvT, Wout, WoutT);

    // qkv = x @ Wqkv + bqkv   (M=16384, N=3072, K=1024) -> bf16
    gemm_qkv<<<dim3(128, 24), 256, 0, stream>>>(x_bf, 1024, WqkvT, 1024, bqkv,
                                                qkv, 3072, 1024);

    norm_kv<<<1024, 256, 0, stream>>>(qkv, rnq, kv);
    wprep<<<4096, 256, 0, stream>>>(WoutT, kv, WbT);

    // y = rnq .* (q @ W'_b) + bout   (M=16384, N=1024, K=1024) -> fp32 d_out
    gemm_out<<<dim3(256, 8), 256, 0, stream>>>(qkv, 3072, WbT, 1024, bout, rnq,
                                               out, 1024, 1024);
}

// Round 7
// 384.797 us; speedup vs baseline: 1.0666x; 1.0568x over previous
//
#include <hip/hip_runtime.h>

// ---------- types / helpers ----------
typedef __attribute__((ext_vector_type(8))) short short8;   // 8 bf16 = 4 VGPRs
typedef __attribute__((ext_vector_type(4))) float f32x4;

__device__ __forceinline__ float bf2f(unsigned short u) {
    union { unsigned int i; float f; } x; x.i = ((unsigned int)u) << 16; return x.f;
}
__device__ __forceinline__ unsigned short f2bf(float f) {
    union { float f; unsigned int i; } x; x.f = f;
    unsigned int r = x.i + 0x7fffu + ((x.i >> 16) & 1u);   // RTNE
    return (unsigned short)(r >> 16);
}
__device__ __forceinline__ void async_copy16(const void* g, void* l) {
    __builtin_amdgcn_global_load_lds(
        (const __attribute__((address_space(1))) void*)g,
        (__attribute__((address_space(3))) void*)l,
        16, 0, 0);
}
__device__ __forceinline__ float sumsq8(short8 v, float s) {
    #pragma unroll
    for (int e = 0; e < 8; e++) {
        float f = bf2f((unsigned short)v[e]);
        s = fmaf(f, f, s);
    }
    return s;
}

// ---------- prep: x fp32->bf16 (blocks 0..8191) + weight transposes (8192..12287) ----------
__global__ __launch_bounds__(256) void prep(const float* __restrict__ x,
                                            unsigned short* __restrict__ x_bf,
                                            const float* __restrict__ Wqkv,
                                            unsigned short* __restrict__ WqkvT,
                                            const float* __restrict__ Wout,
                                            unsigned short* __restrict__ WoutT,
                                            float* __restrict__ kv) {
    __shared__ float tile[32][33];
    const int bid = blockIdx.x;
    if (bid < 8192) {
        if (bid < 4)    // zero kv[4096] (re-poisoned to 0xAA each call)
            *(float4*)&kv[bid * 1024 + threadIdx.x * 4] = make_float4(0.f, 0.f, 0.f, 0.f);
        int i = (bid * 256 + threadIdx.x) * 8;
        float4 v0 = *(const float4*)&x[i];
        float4 v1 = *(const float4*)&x[i + 4];
        ushort4 o0, o1;
        o0.x = f2bf(v0.x); o0.y = f2bf(v0.y); o0.z = f2bf(v0.z); o0.w = f2bf(v0.w);
        o1.x = f2bf(v1.x); o1.y = f2bf(v1.y); o1.z = f2bf(v1.z); o1.w = f2bf(v1.w);
        *(ushort4*)&x_bf[i]     = o0;
        *(ushort4*)&x_bf[i + 4] = o1;
    } else {
        const int tb = bid - 8192;             // 4096 transpose tiles (was dim3(128,32))
        const int xb = tb & 127, by = (tb >> 7) * 32;
        const int R = 1024;
        const float* in; unsigned short* out; int C, bx;
        if (xb < 96) { in = Wqkv; out = WqkvT; C = 3072; bx = xb * 32; }
        else         { in = Wout; out = WoutT; C = 1024; bx = (xb - 96) * 32; }
        int tx = threadIdx.x & 31, ty = threadIdx.x >> 5;
        #pragma unroll
        for (int r = ty; r < 32; r += 8)
            tile[r][tx] = in[(size_t)(by + r) * C + bx + tx];
        __syncthreads();
        #pragma unroll
        for (int r = ty; r < 32; r += 8)
            out[(size_t)(bx + r) * R + by + tx] = f2bf(tile[tx][r]);
    }
}

// ---------- GEMM1: qkv[M,3072] = x[M,1024] @ WqkvT^T + bqkv, bf16 out (R4-proven core) ----------
// Flat grid 3072, swizzled: all 24 n-blocks of one A-strip on the same XCD, temporally adjacent.
__global__ __launch_bounds__(256) void gemm_qkv(const unsigned short* __restrict__ A, int lda,
                                                const unsigned short* __restrict__ Bt, int ldb,
                                                const float* __restrict__ bias,
                                                unsigned short* __restrict__ C, int ldc, int K) {
    __shared__ short smem[17408];
    short* As = smem;
    short* Bs = smem + 8192;

    const int tid    = threadIdx.x;
    const int lane   = tid & 63;
    const int wid    = tid >> 6;
    const int wave_m = wid >> 1, wave_n = wid & 1;
    const int quad   = lane >> 4;
    const int l16    = lane & 15;

    // swizzle: groups of 192 = 8 m-strips x 24 n; id&7 = m_local = XCD
    const int id   = blockIdx.x;
    const int mg   = id / 192, g = id % 192;
    const int m0   = (mg * 8 + (g & 7)) * 128;
    const int n0   = (g >> 3) * 128;

    size_t aoff[4], boff[4];
    int ldst[4];
    #pragma unroll
    for (int j = 0; j < 4; j++) {
        const int L = j * 256 + tid;
        const int r = L >> 3;
        const int c = ((L & 7) ^ (r & 7)) * 8;
        aoff[j] = (size_t)(m0 + r) * lda + c;
        boff[j] = (size_t)(n0 + r) * ldb + c;
        ldst[j] = L * 8;
    }
    int rA[4], rB[4];
    #pragma unroll
    for (int i = 0; i < 4; i++) { rA[i] = wave_m * 64 + i * 16 + l16;
                                  rB[i] = wave_n * 64 + i * 16 + l16; }

    f32x4 acc[4][4] = {};

    for (int k0 = 0; k0 < K; k0 += 64) {
        __syncthreads();
        #pragma unroll
        for (int j = 0; j < 4; j++) async_copy16(A  + aoff[j] + k0, &As[ldst[j]]);
        #pragma unroll
        for (int j = 0; j < 4; j++) async_copy16(Bt + boff[j] + k0, &Bs[ldst[j]]);
        __syncthreads();

        #pragma unroll
        for (int kk = 0; kk < 2; kk++) {
            short8 af[4], bfr[4];
            #pragma unroll
            for (int i = 0; i < 4; i++)
                af[i]  = *(const short8*)&As[rA[i] * 64 + (((quad + kk * 4) ^ (rA[i] & 7)) * 8)];
            #pragma unroll
            for (int j = 0; j < 4; j++)
                bfr[j] = *(const short8*)&Bs[rB[j] * 64 + (((quad + kk * 4) ^ (rB[j] & 7)) * 8)];
            #pragma unroll
            for (int i = 0; i < 4; i++)
                #pragma unroll
                for (int j = 0; j < 4; j++)
                    acc[i][j] = __builtin_amdgcn_mfma_f32_16x16x32_bf16(af[i], bfr[j], acc[i][j], 0, 0, 0);
        }
    }

    // C/D layout: col = lane&15, row = quad*4 + r   [m89/m91]
    __syncthreads();
    unsigned short* tile = (unsigned short*)smem;   // [128][136] padded
    #pragma unroll
    for (int j = 0; j < 4; j++) {
        const int tcol = wave_n * 64 + j * 16 + l16;
        const float bv = bias[n0 + tcol];
        #pragma unroll
        for (int i = 0; i < 4; i++) {
            const int trow = wave_m * 64 + i * 16 + quad * 4;
            #pragma unroll
            for (int r = 0; r < 4; r++)
                tile[(trow + r) * 136 + tcol] = f2bf(acc[i][j][r] + bv);
        }
    }
    __syncthreads();
    #pragma unroll
    for (int p = 0; p < 4; p++) {
        const int row = p * 32 + (tid >> 3);
        const int col = (tid & 7) * 16;
        short8 v0 = *(const short8*)&tile[row * 136 + col];
        short8 v1 = *(const short8*)&tile[row * 136 + col + 8];
        *(short8*)&C[(size_t)(m0 + row) * ldc + n0 + col]     = v0;
        *(short8*)&C[(size_t)(m0 + row) * ldc + n0 + col + 8] = v1;
    }
}

// ---------- GEMM2: out = rsqrt(|q|^2) .* (q @ WbT_b^T) + bout, fp32 out ----------
// BM=BN=128 (R4-proven core), flat grid 1024 swizzled (8m x 8n groups).
// q row sumsq fused into the K-loop from the af fragments (block-local, no atomics).
__global__ __launch_bounds__(256) void gemm_out(const unsigned short* __restrict__ A, int lda,
                                                const unsigned short* __restrict__ Bt, int ldb,
                                                const float* __restrict__ bias,
                                                float* __restrict__ C, int ldc, int K) {
    __shared__ short smem[16384];
    short* As = smem;
    short* Bs = smem + 8192;

    const int tid    = threadIdx.x;
    const int lane   = tid & 63;
    const int wid    = tid >> 6;
    const int wave_m = wid >> 1, wave_n = wid & 1;
    const int quad   = lane >> 4;
    const int l16    = lane & 15;

    // swizzle: groups of 64 = 8 m-strips x 8 n; id&7 = m_local = XCD
    const int id   = blockIdx.x;
    const int mblk = (id >> 6) * 8 + (id & 7);
    const int m0   = mblk * 128;
    const int n0   = ((id >> 3) & 7) * 128;

    Bt += (size_t)(mblk >> 5) * 1048576;   // batch = m0/4096

    size_t aoff[4], boff[4];
    int ldst[4];
    #pragma unroll
    for (int j = 0; j < 4; j++) {
        const int L = j * 256 + tid;
        const int r = L >> 3;
        const int c = ((L & 7) ^ (r & 7)) * 8;
        aoff[j] = (size_t)(m0 + r) * lda + c;
        boff[j] = (size_t)(n0 + r) * ldb + c;
        ldst[j] = L * 8;
    }
    int rA[4], rB[4];
    #pragma unroll
    for (int i = 0; i < 4; i++) { rA[i] = wave_m * 64 + i * 16 + l16;
                                  rB[i] = wave_n * 64 + i * 16 + l16; }

    f32x4 acc[4][4] = {};
    float sq[4] = {0.f, 0.f, 0.f, 0.f};   // partial sumsq of q row rA[i]

    for (int k0 = 0; k0 < K; k0 += 64) {
        __syncthreads();
        #pragma unroll
        for (int j = 0; j < 4; j++) async_copy16(A  + aoff[j] + k0, &As[ldst[j]]);
        #pragma unroll
        for (int j = 0; j < 4; j++) async_copy16(Bt + boff[j] + k0, &Bs[ldst[j]]);
        __syncthreads();

        #pragma unroll
        for (int kk = 0; kk < 2; kk++) {
            short8 af[4], bfr[4];
            #pragma unroll
            for (int i = 0; i < 4; i++) {
                af[i] = *(const short8*)&As[rA[i] * 64 + (((quad + kk * 4) ^ (rA[i] & 7)) * 8)];
                sq[i] = sumsq8(af[i], sq[i]);
            }
            #pragma unroll
            for (int j = 0; j < 4; j++)
                bfr[j] = *(const short8*)&Bs[rB[j] * 64 + (((quad + kk * 4) ^ (rB[j] & 7)) * 8)];
            #pragma unroll
            for (int i = 0; i < 4; i++)
                #pragma unroll
                for (int j = 0; j < 4; j++)
                    acc[i][j] = __builtin_amdgcn_mfma_f32_16x16x32_bf16(af[i], bfr[j], acc[i][j], 0, 0, 0);
        }
    }

    // reduce sumsq over the 4 quads (lanes stride 16): lane l16 then holds row rA[i]'s total
    #pragma unroll
    for (int i = 0; i < 4; i++) {
        sq[i] += __shfl_xor(sq[i], 16, 64);
        sq[i] += __shfl_xor(sq[i], 32, 64);
    }

    // epilogue: acc * rsqrt(sq[row]) + bias; row = quad*4 + r lives in lane quad*4+r
    #pragma unroll
    for (int i = 0; i < 4; i++) {
        const int growb = m0 + wave_m * 64 + i * 16 + quad * 4;
        const float r0 = rsqrtf(__shfl(sq[i], quad * 4 + 0, 64));
        const float r1 = rsqrtf(__shfl(sq[i], quad * 4 + 1, 64));
        const float r2 = rsqrtf(__shfl(sq[i], quad * 4 + 2, 64));
        const float r3 = rsqrtf(__shfl(sq[i], quad * 4 + 3, 64));
        #pragma unroll
        for (int j = 0; j < 4; j++) {
            const int gcol = n0 + wave_n * 64 + j * 16 + l16;
            const float bv = bias[gcol];
            C[(size_t)(growb + 0) * ldc + gcol] = acc[i][j][0] * r0 + bv;
            C[(size_t)(growb + 1) * ldc + gcol] = acc[i][j][1] * r1 + bv;
            C[(size_t)(growb + 2) * ldc + gcol] = acc[i][j][2] * r2 + bv;
            C[(size_t)(growb + 3) * ldc + gcol] = acc[i][j][3] * r3 + bv;
        }
    }
}

// ---------- kv pool: kv[b][d] = sum_t k_hat[t][d] * v[t][d]  (no q read) ----------
__global__ __launch_bounds__(256) void kv_pool(const unsigned short* __restrict__ qkv,
                                               float* __restrict__ kv) {
    __shared__ float kvbuf[1024];
    const int tid = threadIdx.x, lane = tid & 63, wv = tid >> 6;
    *(float4*)&kvbuf[tid * 4] = make_float4(0.f, 0.f, 0.f, 0.f);
    __syncthreads();

    const int row0 = blockIdx.x * 16 + wv * 4;
    float a[4][4] = {};

    for (int rr = 0; rr < 4; rr++) {
        const size_t base = (size_t)(row0 + rr) * 3072;
        float k2 = 0.f;
        float kf[4][4];
        #pragma unroll
        for (int c = 0; c < 4; c++) {
            ushort4 ku = *(const ushort4*)&qkv[base + 1024 + c * 256 + lane * 4];
            kf[c][0] = bf2f(ku.x); kf[c][1] = bf2f(ku.y);
            kf[c][2] = bf2f(ku.z); kf[c][3] = bf2f(ku.w);
            k2 += kf[c][0]*kf[c][0] + kf[c][1]*kf[c][1] + kf[c][2]*kf[c][2] + kf[c][3]*kf[c][3];
        }
        #pragma unroll
        for (int m = 32; m; m >>= 1) k2 += __shfl_xor(k2, m, 64);
        const float rk = rsqrtf(k2);

        #pragma unroll
        for (int c = 0; c < 4; c++) {
            ushort4 vu = *(const ushort4*)&qkv[base + 2048 + c * 256 + lane * 4];
            a[c][0] += kf[c][0] * rk * bf2f(vu.x);
            a[c][1] += kf[c][1] * rk * bf2f(vu.y);
            a[c][2] += kf[c][2] * rk * bf2f(vu.z);
            a[c][3] += kf[c][3] * rk * bf2f(vu.w);
        }
    }
    #pragma unroll
    for (int c = 0; c < 4; c++)
        #pragma unroll
        for (int i = 0; i < 4; i++)
            atomicAdd(&kvbuf[c * 256 + lane * 4 + i], a[c][i]);
    __syncthreads();
    const int b = blockIdx.x >> 8;
    #pragma unroll
    for (int i = 0; i < 4; i++)
        atomicAdd(&kv[b * 1024 + tid * 4 + i], kvbuf[tid * 4 + i]);
}

// ---------- W'_b^T[n][k] = WoutT[n][k] * kv[b][k]  (bf16) ----------
__global__ __launch_bounds__(256) void wprep(const unsigned short* __restrict__ WoutT,
                                             const float* __restrict__ kv,
                                             unsigned short* __restrict__ WbT) {
    const int b = blockIdx.x >> 10, n = blockIdx.x & 1023, k = threadIdx.x * 4;
    ushort4 w = *(const ushort4*)&WoutT[n * 1024 + k];
    float4 kvv = *(const float4*)&kv[b * 1024 + k];
    ushort4 o;
    o.x = f2bf(bf2f(w.x) * kvv.x);
    o.y = f2bf(bf2f(w.y) * kvv.y);
    o.z = f2bf(bf2f(w.z) * kvv.z);
    o.w = f2bf(bf2f(w.w) * kvv.w);
    *(ushort4*)&WbT[((size_t)b << 20) + n * 1024 + k] = o;
}

extern "C" void kernel_launch(void* const* d_in, const int* in_sizes, int n_in,
                              void* d_out, int out_size, void* d_ws, size_t ws_size,
                              hipStream_t stream) {
    const float* x    = (const float*)d_in[0];   // (4,4096,1024)
    const float* Wqkv = (const float*)d_in[1];   // (1024,3072)
    const float* bqkv = (const float*)d_in[2];   // (3072)
    const float* Wout = (const float*)d_in[3];   // (1024,1024)
    const float* bout = (const float*)d_in[4];   // (1024)
    float* out = (float*)d_out;                  // (4,4096,1024) fp32

    char* ws = (char*)d_ws;
    unsigned short* x_bf  = (unsigned short*)(ws + 0);           // 32 MB; dead after GEMM1
    unsigned short* WbT   = x_bf;                                // 8 MB, reuses x_bf region
    unsigned short* WqkvT = (unsigned short*)(ws + 33554432);    // 6 MB
    unsigned short* WoutT = (unsigned short*)(ws + 39845888);    // 2 MB
    unsigned short* qkv   = (unsigned short*)(ws + 41943040);    // 96 MB
    float* kv             = (float*)(ws + 142606336);            // 16 KB

    prep<<<12288, 256, 0, stream>>>(x, x_bf, Wqkv, WqkvT, Wout, WoutT, kv);

    // qkv = x @ Wqkv + bqkv   (M=16384, N=3072, K=1024) -> bf16
    gemm_qkv<<<3072, 256, 0, stream>>>(x_bf, 1024, WqkvT, 1024, bqkv, qkv, 3072, 1024);

    kv_pool<<<1024, 256, 0, stream>>>(qkv, kv);
    wprep<<<4096, 256, 0, stream>>>(WoutT, kv, WbT);

    // y = rsqrt(|q|^2) .* (q @ W'_b) + bout   (M=16384, N=1024, K=1024) -> fp32 d_out
    gemm_out<<<1024, 256, 0, stream>>>(qkv, 3072, WbT, 1024, bout, out, 1024, 1024);
}